// Round 1
// baseline (201.317 us; speedup 1.0000x reference)
//
#include <hip/hip_runtime.h>

// ConfidenceCalibration: the reference's final reduction is
//   final = (calibrated[:,None] * softmax(logits)).sum(-1) = calibrated
// because softmax rows sum to 1. So the whole Linear->LN->GELU->Linear->softmax
// network is an exact identity on the output. Live path:
//   base  = sigmoid(mean(x, axis=-1))                    [B]
//   idx   = searchsorted(linspace(0,1,NB+1), base, 'right') - 1
//   scale = in_range(idx) ? bin_scaling[idx] : 0
//   out   = clip(base * scale, 0, 1)
// Memory-bound: one pass over x (128 MiB) -> ~21 us at 6.3 TB/s.

__global__ __launch_bounds__(256) void ConfidenceCalibration_44985487458449_kernel(
    const float* __restrict__ x,
    const float* __restrict__ bin_scaling,
    float* __restrict__ out,
    int B, int D, int NB) {
    // one 64-lane wave per row
    const int gwave = (int)((blockIdx.x * blockDim.x + threadIdx.x) >> 6);
    const int lane  = threadIdx.x & 63;
    if (gwave >= B) return;

    const float4* __restrict__ row = (const float4*)(x + (size_t)gwave * (size_t)D);
    const int nvec = D >> 2;  // D is a multiple of 4 (D=1024)

    float s = 0.0f;
    for (int j = lane; j < nvec; j += 64) {
        float4 v = row[j];
        s += (v.x + v.y) + (v.z + v.w);
    }

    // 64-lane butterfly reduction (wave = 64 on CDNA)
    #pragma unroll
    for (int off = 32; off > 0; off >>= 1) {
        s += __shfl_down(s, off, 64);
    }

    if (lane == 0) {
        const float m    = s / (float)D;
        const float base = 1.0f / (1.0f + expf(-m));

        // searchsorted(boundaries, base, side='right') - 1,
        // boundaries = linspace(0, 1, NB+1)
        int count = 0;
        for (int i = 0; i <= NB; ++i) {
            const float b = (float)i / (float)NB;
            count += (base >= b) ? 1 : 0;
        }
        const int idx = count - 1;

        const float scale = (idx >= 0 && idx < NB) ? bin_scaling[idx] : 0.0f;
        const float v     = base * scale;
        out[gwave] = fminf(fmaxf(v, 0.0f), 1.0f);
    }
}

extern "C" void kernel_launch(void* const* d_in, const int* in_sizes, int n_in,
                              void* d_out, int out_size, void* d_ws, size_t ws_size,
                              hipStream_t stream) {
    // setup_inputs order: x, w1, b1, ln_g, ln_b, w2, b2, bin_scaling
    const float* x           = (const float*)d_in[0];
    const float* bin_scaling = (const float*)d_in[7];
    float* out = (float*)d_out;

    const int B  = out_size;              // 32768
    const int D  = in_sizes[0] / B;       // 1024
    const int NB = in_sizes[7];           // 15

    const int threads = 256;              // 4 waves -> 4 rows per block
    const int rows_per_block = threads / 64;
    const int grid = (B + rows_per_block - 1) / rows_per_block;

    ConfidenceCalibration_44985487458449_kernel<<<grid, threads, 0, stream>>>(
        x, bin_scaling, out, B, D, NB);
}

// Round 2
// 199.559 us; speedup vs baseline: 1.0088x; 1.0088x over previous
//
#include <hip/hip_runtime.h>

// ConfidenceCalibration: the reference's final reduction is
//   final = (calibrated[:,None] * softmax(logits)).sum(-1) = calibrated
// because softmax rows sum to 1 (exact to ~1 ulp; verified absmax 0.0 in R1).
// The whole Linear->LN->GELU->Linear->softmax network multiplies the output
// by exactly 1. Live path:
//   base  = sigmoid(mean(x, axis=-1))                    [B]
//   idx   = searchsorted(linspace(0,1,NB+1), base, 'right') - 1
//   scale = in_range(idx) ? bin_scaling[idx] : 0
//   out   = clip(base * scale, 0, 1)
// Memory-bound: one pass over x (128 MiB) -> ~20 us at 6.3 TB/s.
// D=1024 specialized so the per-wave load loop (4x global_load_dwordx4)
// fully unrolls with independent accumulators -> 4 loads in flight per wave.

template <int D>
__device__ __forceinline__ void row_body(const float* __restrict__ x,
                                         const float* __restrict__ bin_scaling,
                                         float* __restrict__ out,
                                         int gwave, int lane, int NB) {
    const float4* __restrict__ row = (const float4*)(x + (size_t)gwave * (size_t)D);
    constexpr int NVEC = D / 4;      // float4s per row
    constexpr int ITER = NVEC / 64;  // per-lane iterations (4 for D=1024)

    // Independent partials -> all ITER loads issued before any dependent add.
    float4 v[ITER];
    #pragma unroll
    for (int i = 0; i < ITER; ++i) v[i] = row[lane + i * 64];

    float s = 0.0f;
    #pragma unroll
    for (int i = 0; i < ITER; ++i) s += (v[i].x + v[i].y) + (v[i].z + v[i].w);

    // 64-lane butterfly reduction (wave = 64 on CDNA)
    #pragma unroll
    for (int off = 32; off > 0; off >>= 1) s += __shfl_down(s, off, 64);

    if (lane == 0) {
        const float m    = s / (float)D;
        const float base = 1.0f / (1.0f + expf(-m));

        // searchsorted(boundaries, base, 'right') - 1, boundaries = linspace(0,1,NB+1)
        int count = 0;
        for (int i = 0; i <= NB; ++i) {
            const float b = (float)i / (float)NB;
            count += (base >= b) ? 1 : 0;
        }
        const int idx = count - 1;

        const float scale = (idx >= 0 && idx < NB) ? bin_scaling[idx] : 0.0f;
        const float v0    = base * scale;
        out[gwave] = fminf(fmaxf(v0, 0.0f), 1.0f);
    }
}

__global__ __launch_bounds__(256) void ConfidenceCalibration_44985487458449_kernel(
    const float* __restrict__ x,
    const float* __restrict__ bin_scaling,
    float* __restrict__ out,
    int B, int D, int NB) {
    const int gwave = (int)((blockIdx.x * blockDim.x + threadIdx.x) >> 6);
    const int lane  = threadIdx.x & 63;
    if (gwave >= B) return;

    if (D == 1024) {
        row_body<1024>(x, bin_scaling, out, gwave, lane, NB);
        return;
    }

    // Generic fallback (any D % 4 == 0)
    const float4* __restrict__ row = (const float4*)(x + (size_t)gwave * (size_t)D);
    const int nvec = D >> 2;
    float s = 0.0f;
    for (int j = lane; j < nvec; j += 64) {
        float4 v = row[j];
        s += (v.x + v.y) + (v.z + v.w);
    }
    #pragma unroll
    for (int off = 32; off > 0; off >>= 1) s += __shfl_down(s, off, 64);
    if (lane == 0) {
        const float m    = s / (float)D;
        const float base = 1.0f / (1.0f + expf(-m));
        int count = 0;
        for (int i = 0; i <= NB; ++i) {
            const float b = (float)i / (float)NB;
            count += (base >= b) ? 1 : 0;
        }
        const int idx = count - 1;
        const float scale = (idx >= 0 && idx < NB) ? bin_scaling[idx] : 0.0f;
        const float v0    = base * scale;
        out[gwave] = fminf(fmaxf(v0, 0.0f), 1.0f);
    }
}

extern "C" void kernel_launch(void* const* d_in, const int* in_sizes, int n_in,
                              void* d_out, int out_size, void* d_ws, size_t ws_size,
                              hipStream_t stream) {
    // setup_inputs order: x, w1, b1, ln_g, ln_b, w2, b2, bin_scaling
    const float* x           = (const float*)d_in[0];
    const float* bin_scaling = (const float*)d_in[7];
    float* out = (float*)d_out;

    const int B  = out_size;              // 32768
    const int D  = in_sizes[0] / B;       // 1024
    const int NB = in_sizes[7];           // 15

    const int threads = 256;              // 4 waves -> 4 rows per block
    const int rows_per_block = threads / 64;
    const int grid = (B + rows_per_block - 1) / rows_per_block;

    ConfidenceCalibration_44985487458449_kernel<<<grid, threads, 0, stream>>>(
        x, bin_scaling, out, B, D, NB);
}